// Round 1
// baseline (588.871 us; speedup 1.0000x reference)
//
#include <hip/hip_runtime.h>
#include <hip/hip_cooperative_groups.h>
#include <math.h>

namespace cg = cooperative_groups;

// Problem constants: x [16,64,256,256] f32, mask [16,256,256] i32
#define BATCH 16
#define CH    64
#define HW4   16384          // 256*256/4 (float4 units)
#define NBLKA 2048           // 128 pixel-blocks/batch * 16 batches (128-thr blocks)

#define RED4(t)                                                   \
    vmax.x = fmaxf(vmax.x, (t).x); vmax.y = fmaxf(vmax.y, (t).y); \
    vmax.z = fmaxf(vmax.z, (t).z); vmax.w = fmaxf(vmax.w, (t).w); \
    vmin.x = fminf(vmin.x, (t).x); vmin.y = fminf(vmin.y, (t).y); \
    vmin.z = fminf(vmin.z, (t).z); vmin.w = fminf(vmin.w, (t).w); \
    vsum.x += (t).x; vsum.y += (t).y; vsum.z += (t).z; vsum.w += (t).w;

#define NORMW(dst, src, m, r)                                  \
    (dst).x = (mk.x == 1) ? ((src).x - (m)) * (r) : 0.0f;      \
    (dst).y = (mk.y == 1) ? ((src).y - (m)) * (r) : 0.0f;      \
    (dst).z = (mk.z == 1) ? ((src).z - (m)) * (r) : 0.0f;      \
    (dst).w = (mk.w == 1) ? ((src).w - (m)) * (r) : 0.0f;

// Fused pool+stats+normalize. Cooperative launch: 2048 blocks of 128 thr =
// 8 blocks/CU x 2 waves = 16 waves/CU. __launch_bounds__(128,4) caps VGPR
// at 128 -> 4 waves/EU capacity = exactly 8 blocks/CU, so full grid is
// co-resident and grid.sync() is legal.
//
// Registers held across grid.sync(): vmax/vmean/vmin (12) + mk (4).
// out is written exactly ONCE (the old 2-kernel split wrote it, re-read it,
// re-read mask, and re-wrote it: ~29.4 MB extra HBM traffic + a launch).
__global__ __launch_bounds__(128, 4) void fused_kernel(
    const float* __restrict__ x, const int* __restrict__ mask,
    float* __restrict__ out, float* __restrict__ part)
{
    const int b    = blockIdx.x >> 7;           // batch
    const int pblk = blockIdx.x & 127;          // pixel-block within batch
    const int idx4 = pblk * 128 + threadIdx.x;  // float4 index in [0, HW4)

    const float4* xb = (const float4*)x + (size_t)b * CH * HW4 + idx4;

    float4 vmax = make_float4(-INFINITY, -INFINITY, -INFINITY, -INFINITY);
    float4 vmin = make_float4( INFINITY,  INFINITY,  INFINITY,  INFINITY);
    float4 vsum = make_float4(0.f, 0.f, 0.f, 0.f);

    // 8 channels in flight (128 B/thread outstanding): keeps HBM saturated
    // at 16 waves/CU. ~70 VGPRs, fits the 128 cap without spills.
    for (int c0 = 0; c0 < CH; c0 += 8) {
        float4 t[8];
#pragma unroll
        for (int j = 0; j < 8; ++j)
            t[j] = xb[(size_t)(c0 + j) * HW4];
#pragma unroll
        for (int j = 0; j < 8; ++j) { RED4(t[j]); }
    }

    const float inv = 1.0f / 64.0f;
    float4 vmean = make_float4(vsum.x * inv, vsum.y * inv, vsum.z * inv, vsum.w * inv);

    // masked partial sums for this thread's 4 pixels
    const int4 mk = ((const int4*)mask)[(size_t)b * HW4 + idx4];
    float vals[7] = {0.f, 0.f, 0.f, 0.f, 0.f, 0.f, 0.f}; // cnt, S1[3], S2[3]
    if (mk.x == 1) { vals[0] += 1.f;
        vals[1] += vmax.x;  vals[4] += vmax.x  * vmax.x;
        vals[2] += vmean.x; vals[5] += vmean.x * vmean.x;
        vals[3] += vmin.x;  vals[6] += vmin.x  * vmin.x; }
    if (mk.y == 1) { vals[0] += 1.f;
        vals[1] += vmax.y;  vals[4] += vmax.y  * vmax.y;
        vals[2] += vmean.y; vals[5] += vmean.y * vmean.y;
        vals[3] += vmin.y;  vals[6] += vmin.y  * vmin.y; }
    if (mk.z == 1) { vals[0] += 1.f;
        vals[1] += vmax.z;  vals[4] += vmax.z  * vmax.z;
        vals[2] += vmean.z; vals[5] += vmean.z * vmean.z;
        vals[3] += vmin.z;  vals[6] += vmin.z  * vmin.z; }
    if (mk.w == 1) { vals[0] += 1.f;
        vals[1] += vmax.w;  vals[4] += vmax.w  * vmax.w;
        vals[2] += vmean.w; vals[5] += vmean.w * vmean.w;
        vals[3] += vmin.w;  vals[6] += vmin.w  * vmin.w; }

    // wave (64-lane) shuffle reduction
    for (int off = 32; off > 0; off >>= 1) {
#pragma unroll
        for (int k = 0; k < 7; ++k)
            vals[k] += __shfl_down(vals[k], off, 64);
    }

    // cross-wave (2 waves) LDS reduction -> one contention-free slot per block
    __shared__ float red[2][8];
    const int lane = threadIdx.x & 63;
    const int wid  = threadIdx.x >> 6;
    if (lane == 0) {
#pragma unroll
        for (int k = 0; k < 7; ++k) red[wid][k] = vals[k];
    }
    __syncthreads();
    if (threadIdx.x < 7)
        part[blockIdx.x * 8 + threadIdx.x] = red[0][threadIdx.x] + red[1][threadIdx.x];

    // grid-wide sync: partials from all XCDs become visible (cooperative
    // grid.sync() performs the device-scope release/acquire).
    cg::this_grid().sync();

    // stats finalization: redundant per-block reduce of batch b's 128 partial
    // slots (4 KB, L2-resident). One wave does it.
    __shared__ float sstat[6];   // mean[3], rstd[3]
    if (threadIdx.x < 64) {
        const float* pb = part + (size_t)(b * 128 + threadIdx.x * 2) * 8;
        float s[7];
#pragma unroll
        for (int k = 0; k < 7; ++k) s[k] = pb[k] + pb[8 + k];
        for (int off = 32; off > 0; off >>= 1) {
#pragma unroll
            for (int k = 0; k < 7; ++k)
                s[k] += __shfl_down(s[k], off, 64);
        }
        if (threadIdx.x == 0) {
            const float cnt = s[0];
#pragma unroll
            for (int c = 0; c < 3; ++c) {
                const float S1 = s[1 + c];
                const float S2 = s[4 + c];
                sstat[c]     = S1 / cnt;
                sstat[3 + c] = 1.0f / sqrtf((S2 - S1 * S1 / cnt) / (cnt - 1.0f));
            }
        }
    }
    __syncthreads();

    // normalize the register-held pooled values; write out ONCE.
    float4* ob = (float4*)out + (size_t)b * 3 * HW4 + idx4;
    float4 o;
    NORMW(o, vmax,  sstat[0], sstat[3]);  ob[0]       = o;   // c=0: max
    NORMW(o, vmean, sstat[1], sstat[4]);  ob[HW4]     = o;   // c=1: mean
    NORMW(o, vmin,  sstat[2], sstat[5]);  ob[2 * HW4] = o;   // c=2: min
}

extern "C" void kernel_launch(void* const* d_in, const int* in_sizes, int n_in,
                              void* d_out, int out_size, void* d_ws, size_t ws_size,
                              hipStream_t stream)
{
    const float* x    = (const float*)d_in[0];
    const int*   mask = (const int*)d_in[1];
    float*       out  = (float*)d_out;
    float*       part = (float*)d_ws;   // 2048 * 8 floats = 64 KB

    void* args[] = {(void*)&x, (void*)&mask, (void*)&out, (void*)&part};
    hipLaunchCooperativeKernel((const void*)fused_kernel,
                               dim3(NBLKA), dim3(128), args, 0, stream);
}

// Round 2
// 371.203 us; speedup vs baseline: 1.5864x; 1.5864x over previous
//
#include <hip/hip_runtime.h>
#include <math.h>

// Problem constants: x [16,64,256,256] f32, mask [16,256,256] i32
#define BATCH 16
#define CH    64
#define HW    65536          // 256*256
#define HW4   16384          // HW/4 (float4 units)
#define NBLKA 2048           // pool: 128 blocks/batch * 16 batches (128-thr blocks)

#define RED4(t)                                                   \
    vmax.x = fmaxf(vmax.x, (t).x); vmax.y = fmaxf(vmax.y, (t).y); \
    vmax.z = fmaxf(vmax.z, (t).z); vmax.w = fmaxf(vmax.w, (t).w); \
    vmin.x = fminf(vmin.x, (t).x); vmin.y = fminf(vmin.y, (t).y); \
    vmin.z = fminf(vmin.z, (t).z); vmin.w = fminf(vmin.w, (t).w); \
    vsum.x += (t).x; vsum.y += (t).y; vsum.z += (t).z; vsum.w += (t).w;

// ws: per-block partials, 8 floats each: cnt, S1[3], S2[3], pad.
// Contention-free slots -> no init needed (every slot written before read).

// Grid is 2048 blocks = 8 blocks/CU max, so the old (128,8) bound (VGPR<=64)
// bought no extra residency. (128,4) -> VGPR cap 128, which lets the channel
// loop run 8 loads deep (128 B/thread outstanding) at identical occupancy.
__global__ __launch_bounds__(128, 4) void pool_stats_kernel(
    const float* __restrict__ x, const int* __restrict__ mask,
    float* __restrict__ out, float* __restrict__ part)
{
    const int b    = blockIdx.x >> 7;           // batch
    const int pblk = blockIdx.x & 127;          // pixel-block within batch
    const int idx4 = pblk * 128 + threadIdx.x;  // float4 index in [0, HW4)

    const float4* xb = (const float4*)x + (size_t)b * CH * HW4 + idx4;

    // issue the mask load first; its latency hides under the x reads
    const int4 mk = ((const int4*)mask)[(size_t)b * HW4 + idx4];

    float4 vmax = make_float4(-INFINITY, -INFINITY, -INFINITY, -INFINITY);
    float4 vmin = make_float4( INFINITY,  INFINITY,  INFINITY,  INFINITY);
    float4 vsum = make_float4(0.f, 0.f, 0.f, 0.f);

    // 8 channels in flight: t[8] = 32 VGPRs of load data, ~60 VGPRs total.
    for (int c0 = 0; c0 < CH; c0 += 8) {
        float4 t[8];
#pragma unroll
        for (int j = 0; j < 8; ++j)
            t[j] = xb[(size_t)(c0 + j) * HW4];
#pragma unroll
        for (int j = 0; j < 8; ++j) { RED4(t[j]); }
    }

    const float inv = 1.0f / 64.0f;
    float4 vmean = make_float4(vsum.x * inv, vsum.y * inv, vsum.z * inv, vsum.w * inv);

    // write pooled channels [max, mean, min] into d_out [B,3,H,W]
    float4* ob = (float4*)out + (size_t)b * 3 * HW4 + idx4;
    ob[0]       = vmax;
    ob[HW4]     = vmean;
    ob[2 * HW4] = vmin;

    // masked partial sums for this thread's 4 pixels
    float vals[7] = {0.f, 0.f, 0.f, 0.f, 0.f, 0.f, 0.f}; // cnt, S1[3], S2[3]
    if (mk.x == 1) { vals[0] += 1.f;
        vals[1] += vmax.x;  vals[4] += vmax.x  * vmax.x;
        vals[2] += vmean.x; vals[5] += vmean.x * vmean.x;
        vals[3] += vmin.x;  vals[6] += vmin.x  * vmin.x; }
    if (mk.y == 1) { vals[0] += 1.f;
        vals[1] += vmax.y;  vals[4] += vmax.y  * vmax.y;
        vals[2] += vmean.y; vals[5] += vmean.y * vmean.y;
        vals[3] += vmin.y;  vals[6] += vmin.y  * vmin.y; }
    if (mk.z == 1) { vals[0] += 1.f;
        vals[1] += vmax.z;  vals[4] += vmax.z  * vmax.z;
        vals[2] += vmean.z; vals[5] += vmean.z * vmean.z;
        vals[3] += vmin.z;  vals[6] += vmin.z  * vmin.z; }
    if (mk.w == 1) { vals[0] += 1.f;
        vals[1] += vmax.w;  vals[4] += vmax.w  * vmax.w;
        vals[2] += vmean.w; vals[5] += vmean.w * vmean.w;
        vals[3] += vmin.w;  vals[6] += vmin.w  * vmin.w; }

    // wave (64-lane) shuffle reduction
    for (int off = 32; off > 0; off >>= 1) {
#pragma unroll
        for (int k = 0; k < 7; ++k)
            vals[k] += __shfl_down(vals[k], off, 64);
    }

    // cross-wave (2 waves) LDS reduction -> one contention-free slot per block
    __shared__ float red[2][8];
    const int lane = threadIdx.x & 63;
    const int wid  = threadIdx.x >> 6;
    if (lane == 0) {
#pragma unroll
        for (int k = 0; k < 7; ++k) red[wid][k] = vals[k];
    }
    __syncthreads();
    if (threadIdx.x < 7) {
        const int k = threadIdx.x;
        part[blockIdx.x * 8 + k] = red[0][k] + red[1][k];
    }
}

// One block per 256 float4s of out; folds stats finalization (redundant
// per-block reduce of 128 partial slots, ~4 KB from L2) + masked normalize.
__global__ __launch_bounds__(256) void norm_kernel(
    float* __restrict__ out, const int* __restrict__ mask,
    const float* __restrict__ part)
{
    const int i4   = blockIdx.x * 256 + threadIdx.x;   // [0, 3*B*HW4)
    const int bc   = i4 >> 14;                         // (b*3 + c)
    const int idx4 = i4 & (HW4 - 1);
    const int b    = bc / 3;

    // redundant stats reduce: batch b's 128 partial slots (2 per lane)
    __shared__ float sstat[6];   // mean[3], rstd[3]
    if (threadIdx.x < 64) {
        const float* pb = part + (size_t)(b * 128 + threadIdx.x * 2) * 8;
        float s[7];
#pragma unroll
        for (int k = 0; k < 7; ++k) s[k] = pb[k] + pb[8 + k];
        for (int off = 32; off > 0; off >>= 1) {
#pragma unroll
            for (int k = 0; k < 7; ++k)
                s[k] += __shfl_down(s[k], off, 64);
        }
        if (threadIdx.x == 0) {
            const float cnt = s[0];
#pragma unroll
            for (int c = 0; c < 3; ++c) {
                const float S1 = s[1 + c];
                const float S2 = s[4 + c];
                sstat[c]     = S1 / cnt;
                sstat[3 + c] = 1.0f / sqrtf((S2 - S1 * S1 / cnt) / (cnt - 1.0f));
            }
        }
    }
    __syncthreads();

    const int   c    = bc - b * 3;
    const float mean = sstat[c];
    const float rstd = sstat[3 + c];

    float4 v = ((const float4*)out)[i4];
    int4 mk  = ((const int4*)mask)[(size_t)b * HW4 + idx4];
    v.x = (mk.x == 1) ? (v.x - mean) * rstd : 0.0f;
    v.y = (mk.y == 1) ? (v.y - mean) * rstd : 0.0f;
    v.z = (mk.z == 1) ? (v.z - mean) * rstd : 0.0f;
    v.w = (mk.w == 1) ? (v.w - mean) * rstd : 0.0f;
    ((float4*)out)[i4] = v;
}

extern "C" void kernel_launch(void* const* d_in, const int* in_sizes, int n_in,
                              void* d_out, int out_size, void* d_ws, size_t ws_size,
                              hipStream_t stream)
{
    const float* x    = (const float*)d_in[0];
    const int*   mask = (const int*)d_in[1];
    float*       out  = (float*)d_out;
    float*       part = (float*)d_ws;

    pool_stats_kernel<<<NBLKA, 128, 0, stream>>>(x, mask, out, part);
    norm_kernel<<<3 * BATCH * HW4 / 256, 256, 0, stream>>>(out, mask, part);
}